// Round 18
// baseline (148.969 us; speedup 1.0000x reference)
//
#include <hip/hip_runtime.h>
#include <math.h>

// Problem constants (B, S, E, WIN) = (8, 2048, 512, 11)
#define B_    8
#define S_    2048
#define E_    512
#define WIN_  11
#define WW    5              // WIN/2
#define F4C   1408           // float4 per W row (5632/4)
#define E4C   128            // float4 per x row (512/4)
#define PSTR  (B_ * WIN_)    // 88 gate logits per s

// ---- DPP wave-sum: 6 VALU ops, zero DS-pipe traffic. Full sum -> lane 63.
template <int CTRL, int RMASK>
__device__ __forceinline__ float dpp_add(float v) {
    int sh = __builtin_amdgcn_update_dpp(0, __float_as_int(v),
                                         CTRL, RMASK, 0xF, true);
    return v + __int_as_float(sh);
}
__device__ __forceinline__ float wave_sum63(float v) {
    v = dpp_add<0x111, 0xF>(v);   // row_shr:1
    v = dpp_add<0x112, 0xF>(v);   // row_shr:2
    v = dpp_add<0x114, 0xF>(v);   // row_shr:4
    v = dpp_add<0x118, 0xF>(v);   // row_shr:8
    v = dpp_add<0x142, 0xA>(v);   // row_bcast:15
    v = dpp_add<0x143, 0xC>(v);   // row_bcast:31 -> lane 63 = full sum
    return v;
}

__device__ __forceinline__ float tanh_fast(float v) {
    const float e = __expf(v + v);
    return 1.f - 2.f / (e + 1.f);
}

// ---------------------------------------------------------------------------
// R18 = R17 with the staging-index bug fixed (LDS dest was j*128, OOB; must
// be the wave-uniform base &Wb[buf][j*64] — gl_lds adds lane*16 itself).
//
// SINGLE-WAVE workgroups (64 thr), barrier-free counted-vmcnt pipeline:
//   - 1 wave per s -> no s_barrier in the stream loop (vmcnt is per-wave,
//     WAR is program order within the wave)
//   - STAGE(next: 19 gl_lds) -> s_waitcnt vmcnt(19) [waits ONLY for the
//     current chunk; the just-issued 19 fly through compute] -> compute
//   - LDS 39.3 KB dbuf -> 4 blocks/CU = 4 independent self-paced streams
//     per CU, no barrier alignment between them (R7-R16's ~70% duty cap).
// Chunk = (wp, e-half): 11 W gl_lds (NT) + 8 x gl_lds. acc[8][11] in VGPRs.
// DPP reduce -> gates (wave-private LDS) -> sigmoid -> score + tanh.
// ---------------------------------------------------------------------------
__global__ __launch_bounds__(64)
void win_attn_fused(const float* __restrict__ x,
                    const float* __restrict__ W,
                    const float* __restrict__ bias,
                    float* __restrict__ out)
{
    const int bid  = blockIdx.x;
    const int s    = (bid & 7) * (S_ / 8) + (bid >> 3);   // bijective XCD swizzle
    const int lane = threadIdx.x;                          // 0..63

    const float4* __restrict__ X4 = reinterpret_cast<const float4*>(x);
    const float4* __restrict__ Ws = reinterpret_cast<const float4*>(W)
                                    + (size_t)s * (WIN_ * F4C);

    __shared__ float4 Wb[2][WIN_ * 64];   // 2 x 11 KB
    __shared__ float4 xb[2][B_ * 64];     // 2 x 8 KB
    __shared__ float gates[PSTR];

    // stage chunk c = (wp, h): 11 W gl_lds (NT) + 8 x gl_lds, 1 KB each.
    // LDS dest is the wave-uniform row base; HW adds lane*16.
    auto STAGE = [&](int buf, int c) {
        const int wp  = c >> 1;
        const int h   = c & 1;
        const int row = s - WW + wp;
        #pragma unroll
        for (int j = 0; j < WIN_; ++j) {          // W row j
            const float4* src = Ws + (size_t)j * F4C + wp * E4C + h * 64 + lane;
            __builtin_amdgcn_global_load_lds(
                (const __attribute__((address_space(1))) void*)src,
                (__attribute__((address_space(3))) void*)&Wb[buf][j * 64],
                16, 0, 2 /* NT: one-shot W stream */);
        }
        #pragma unroll
        for (int j = 0; j < B_; ++j) {            // x batch j
            const float4* src = X4 + ((size_t)j * S_ + row) * E4C + h * 64 + lane;
            __builtin_amdgcn_global_load_lds(
                (const __attribute__((address_space(1))) void*)src,
                (__attribute__((address_space(3))) void*)&xb[buf][j * 64],
                16, 0, 0);
        }
    };

    float acc[B_][WIN_];
    #pragma unroll
    for (int b = 0; b < B_; ++b)
        #pragma unroll
        for (int w = 0; w < WIN_; ++w) acc[b][w] = 0.f;

    const int wpLo = (s >= WW) ? 0 : (WW - s);
    const int wpHi = (WIN_ < S_ + WW - s) ? WIN_ : (S_ + WW - s);
    const int cLo  = 2 * wpLo, cHi = 2 * wpHi;

    STAGE(0, cLo);
    int cur = 0;

    #pragma unroll 1
    for (int c = cLo; c < cHi; ++c) {
        const bool more = (c + 1 < cHi);
        if (more) STAGE(cur ^ 1, c + 1);   // next chunk's 19 loads fly over compute

        if (more) asm volatile("s_waitcnt vmcnt(19)" ::: "memory");
        else      asm volatile("s_waitcnt vmcnt(0)"  ::: "memory");
        __builtin_amdgcn_sched_barrier(0);   // rule #18: no ds_read hoist

        // ---- compute chunk c from buf[cur]: 19 ds_read_b128 + 88 FMA4 ----
        float4 xv[B_];
        #pragma unroll
        for (int b = 0; b < B_; ++b) xv[b] = xb[cur][b * 64 + lane];

        #pragma unroll
        for (int w = 0; w < WIN_; ++w) {
            const float4 wv = Wb[cur][w * 64 + lane];
            #pragma unroll
            for (int b = 0; b < B_; ++b) {
                float a = acc[b][w];
                a = fmaf(xv[b].x, wv.x, a);
                a = fmaf(xv[b].y, wv.y, a);
                a = fmaf(xv[b].z, wv.z, a);
                a = fmaf(xv[b].w, wv.w, a);
                acc[b][w] = a;
            }
        }
        __builtin_amdgcn_sched_barrier(0);   // keep compute before next STAGE
        cur ^= 1;
    }

    // ---- DPP reduce (wave-private) -> gates via LDS -> sigmoid ----
    #pragma unroll
    for (int b = 0; b < B_; ++b)
        #pragma unroll
        for (int w = 0; w < WIN_; ++w)
            acc[b][w] = wave_sum63(acc[b][w]);

    if (lane == 63) {
        #pragma unroll
        for (int b = 0; b < B_; ++b)
            #pragma unroll
            for (int w = 0; w < WIN_; ++w)
                gates[b * WIN_ + w] = acc[b][w];
    }
    __syncthreads();   // single wave: near-free; orders LDS write->read

    #pragma unroll
    for (int rep = 0; rep < 2; ++rep) {
        const int i = rep * 64 + lane;
        if (i < PSTR) {
            const int w = i % WIN_;
            const float v = gates[i] + bias[s * WIN_ + w];
            gates[i] = 1.f / (1.f + __expf(-v));
        }
    }
    __syncthreads();

    // ---- score + tanh: 1024 (b,e4) outputs over 16 iterations ----
    float4* __restrict__ OUT4 = reinterpret_cast<float4*>(out);
    #pragma unroll
    for (int it = 0; it < 16; ++it) {
        const int i  = it * 64 + lane;    // 0..1023
        const int b  = i >> 7;
        const int e4 = i & 127;
        float4 sc = make_float4(0.f, 0.f, 0.f, 0.f);
        #pragma unroll
        for (int w = 0; w < WIN_; ++w) {
            const int r = s - WW + w;
            if (r >= 0 && r < S_) {
                const float g   = gates[b * WIN_ + w];
                const float4 xv = X4[((size_t)b * S_ + r) * E4C + e4];
                sc.x = fmaf(g, xv.x, sc.x);
                sc.y = fmaf(g, xv.y, sc.y);
                sc.z = fmaf(g, xv.z, sc.z);
                sc.w = fmaf(g, xv.w, sc.w);
            }
        }
        float4 o;
        o.x = tanh_fast(sc.x);
        o.y = tanh_fast(sc.y);
        o.z = tanh_fast(sc.z);
        o.w = tanh_fast(sc.w);
        OUT4[((size_t)b * S_ + s) * E4C + e4] = o;
    }
}

extern "C" void kernel_launch(void* const* d_in, const int* in_sizes, int n_in,
                              void* d_out, int out_size, void* d_ws, size_t ws_size,
                              hipStream_t stream)
{
    const float* x    = (const float*)d_in[0];
    const float* W    = (const float*)d_in[1];
    const float* bias = (const float*)d_in[2];
    float* out        = (float*)d_out;

    win_attn_fused<<<dim3(S_), dim3(64), 0, stream>>>(x, W, bias, out);
}

// Round 19
// 129.615 us; speedup vs baseline: 1.1493x; 1.1493x over previous
//
#include <hip/hip_runtime.h>
#include <math.h>

// Problem constants (B, S, E, WIN) = (8, 2048, 512, 11)
#define B_    8
#define S_    2048
#define E_    512
#define WIN_  11
#define WW    5              // WIN/2
#define F4C   1408           // float4 per W row (5632/4)
#define E4C   128            // float4 per x row (512/4)
#define PSTR  (B_ * WIN_)    // 88 gate logits per s

// ---- DPP wave-sum: 6 VALU ops, zero DS-pipe traffic. Full sum -> lane 63.
template <int CTRL, int RMASK>
__device__ __forceinline__ float dpp_add(float v) {
    int sh = __builtin_amdgcn_update_dpp(0, __float_as_int(v),
                                         CTRL, RMASK, 0xF, true);
    return v + __int_as_float(sh);
}
__device__ __forceinline__ float wave_sum63(float v) {
    v = dpp_add<0x111, 0xF>(v);   // row_shr:1
    v = dpp_add<0x112, 0xF>(v);   // row_shr:2
    v = dpp_add<0x114, 0xF>(v);   // row_shr:4
    v = dpp_add<0x118, 0xF>(v);   // row_shr:8
    v = dpp_add<0x142, 0xA>(v);   // row_bcast:15
    v = dpp_add<0x143, 0xC>(v);   // row_bcast:31 -> lane 63 = full sum
    return v;
}

__device__ __forceinline__ float tanh_fast(float v) {
    const float e = __expf(v + v);
    return 1.f - 2.f / (e + 1.f);
}

// ---------------------------------------------------------------------------
// R19 = R16 (best, 129.7 us: half-chunk simple-drain, NT-W, x-in-LDS, DPP
// reduce, fused epilogue) + ONE change: b-SERIAL compute to cut VGPR.
// R16's compute held xv[8](32) + wv[3](12) + acc(24) live -> ~90 VGPR ->
// 5 waves/SIMD -> ~5 blocks/CU, while LDS (19.7 KB) would allow 8.
// Now: preload wv[3], then per-b { 1 ds_read xv -> 12 fmaf } keeps live
// state ~40 + overhead ~60 VGPR -> 8 waves/SIMD tier -> 8 blocks/CU:
// +60% independent stage->drain->compute streams per CU to fill HBM duty.
// (Lesson bank: hand-pipelines R11/R12/R18 all lost to this simple drain;
// occupancy via STRUCTURE, never via forced launch_bounds — R2 spills.)
// ---------------------------------------------------------------------------
__global__ __launch_bounds__(256)
void win_attn_fused(const float* __restrict__ x,
                    const float* __restrict__ W,
                    const float* __restrict__ bias,
                    float* __restrict__ out)
{
    const int bid  = blockIdx.x;
    const int s    = (bid & 7) * (S_ / 8) + (bid >> 3);   // bijective XCD swizzle
    const int tid  = threadIdx.x;
    const int wid  = tid >> 6;      // wave 0..3
    const int lane = tid & 63;

    const float4* __restrict__ X4 = reinterpret_cast<const float4*>(x);
    const float4* __restrict__ Ws = reinterpret_cast<const float4*>(W)
                                    + (size_t)s * (WIN_ * F4C);

    __shared__ float4 Wb[WIN_ * 64];   // 11 KB: [w][64] current (wp, half)
    __shared__ float4 xb[B_ * 64];     // 8 KB:  [b][64] current (row, half)
    __shared__ float gates[PSTR];

    const int w0   = wid * 3;                  // first w-row of this wave
    const int wcnt = (wid == 3) ? 2 : 3;       // wave 3 owns rows 9,10

    float acc[B_][3];
    #pragma unroll
    for (int b = 0; b < B_; ++b)
        #pragma unroll
        for (int j = 0; j < 3; ++j) acc[b][j] = 0.f;

    const int wpLo = (s >= WW) ? 0 : (WW - s);
    const int wpHi = (WIN_ < S_ + WW - s) ? WIN_ : (S_ + WW - s);

    #pragma unroll 1
    for (int c = 2 * wpLo; c < 2 * wpHi; ++c) {
        const int wp  = c >> 1;
        const int h   = c & 1;
        const int row = s - WW + wp;          // valid by construction

        // ---- stage W half-chunk (704 f4, NT) + x half-row (512 f4) ----
        #pragma unroll
        for (int j = 0; j < 3; ++j) {
            const int m = j * 256 + tid;
            if (j < 2 || tid < 192) {          // wave-uniform (m < 704)
                const int w  = m >> 6;
                const int el = m & 63;
                const float4* src = Ws + (size_t)w * F4C + wp * E4C + h * 64 + el;
                __builtin_amdgcn_global_load_lds(
                    (const __attribute__((address_space(1))) void*)src,
                    (__attribute__((address_space(3))) void*)&Wb[m],
                    16, 0, 2 /* NT: one-shot W stream, don't evict x */);
            }
        }
        #pragma unroll
        for (int j = 0; j < 2; ++j) {
            const int n  = j * 256 + tid;      // [0,512)
            const int b  = n >> 6;
            const int el = n & 63;
            const float4* src = X4 + ((size_t)b * S_ + row) * E4C + h * 64 + el;
            __builtin_amdgcn_global_load_lds(
                (const __attribute__((address_space(1))) void*)src,
                (__attribute__((address_space(3))) void*)&xb[n],
                16, 0, 0);
        }
        __syncthreads();   // staging complete (vmcnt drain)

        // ---- compute half-chunk, b-SERIAL to bound live VGPRs (~40) ----
        float4 wv[3];
        #pragma unroll
        for (int j = 0; j < 3; ++j)
            if (j < wcnt) wv[j] = Wb[(w0 + j) * 64 + lane];

        #pragma unroll
        for (int b = 0; b < B_; ++b) {
            const float4 xv = xb[b * 64 + lane];   // one ds_read, then consume
            #pragma unroll
            for (int j = 0; j < 3; ++j)
                if (j < wcnt) {
                    float a = acc[b][j];
                    a = fmaf(xv.x, wv[j].x, a);
                    a = fmaf(xv.y, wv[j].y, a);
                    a = fmaf(xv.z, wv[j].z, a);
                    a = fmaf(xv.w, wv[j].w, a);
                    acc[b][j] = a;
                }
        }

        __syncthreads();   // WAR: reads done before next chunk stages
    }

    // ---- DPP reduce (VALU only) -> gate logits -> sigmoid ----
    #pragma unroll
    for (int b = 0; b < B_; ++b)
        #pragma unroll
        for (int j = 0; j < 3; ++j)
            if (j < wcnt) acc[b][j] = wave_sum63(acc[b][j]);

    if (lane == 63) {
        #pragma unroll
        for (int b = 0; b < B_; ++b)
            #pragma unroll
            for (int j = 0; j < 3; ++j)
                if (j < wcnt) gates[b * WIN_ + w0 + j] = acc[b][j];
    }
    __syncthreads();

    if (tid < PSTR) {
        const int w = tid % WIN_;
        const float v = gates[tid] + bias[s * WIN_ + w];
        gates[tid] = 1.f / (1.f + __expf(-v));
    }
    __syncthreads();

    // ---- score + tanh (identical to R16) ----
    float4* __restrict__ OUT4 = reinterpret_cast<float4*>(out);
    #pragma unroll
    for (int it = 0; it < 4; ++it) {
        const int i  = tid + (it << 8);   // 0..1023 -> (b, e4)
        const int b  = i >> 7;
        const int e4 = i & 127;
        float4 sc = make_float4(0.f, 0.f, 0.f, 0.f);
        #pragma unroll
        for (int w = 0; w < WIN_; ++w) {
            const int r = s - WW + w;
            if (r >= 0 && r < S_) {
                const float g   = gates[b * WIN_ + w];
                const float4 xv = X4[((size_t)b * S_ + r) * E4C + e4];
                sc.x = fmaf(g, xv.x, sc.x);
                sc.y = fmaf(g, xv.y, sc.y);
                sc.z = fmaf(g, xv.z, sc.z);
                sc.w = fmaf(g, xv.w, sc.w);
            }
        }
        float4 o;
        o.x = tanh_fast(sc.x);
        o.y = tanh_fast(sc.y);
        o.z = tanh_fast(sc.z);
        o.w = tanh_fast(sc.w);
        OUT4[((size_t)b * S_ + s) * E4C + e4] = o;
    }
}

extern "C" void kernel_launch(void* const* d_in, const int* in_sizes, int n_in,
                              void* d_out, int out_size, void* d_ws, size_t ws_size,
                              hipStream_t stream)
{
    const float* x    = (const float*)d_in[0];
    const float* W    = (const float*)d_in[1];
    const float* bias = (const float*)d_in[2];
    float* out        = (float*)d_out;

    win_attn_fused<<<dim3(S_), dim3(256), 0, stream>>>(x, W, bias, out);
}